// Round 1
// baseline (1198.494 us; speedup 1.0000x reference)
//
#include <hip/hip_runtime.h>
#include <hip/hip_bf16.h>

#define N_NODES 50000
#define N_EDGES 1600000
#define DF 128

// ---------------- CSR build ----------------

__global__ void deg_kernel(const int* __restrict__ dst, int* __restrict__ deg) {
    int i = blockIdx.x * 256 + threadIdx.x;
    if (i < N_EDGES) atomicAdd(&deg[dst[i]], 1);
}

// single-block exclusive scan over deg -> row_ptr[0..N]
__global__ void scan_kernel(const int* __restrict__ deg, int* __restrict__ row_ptr) {
    __shared__ int buf[1024];
    __shared__ int carry_s;
    const int tid = threadIdx.x;
    if (tid == 0) { carry_s = 0; row_ptr[0] = 0; }
    __syncthreads();
    for (int base = 0; base < N_NODES; base += 1024) {
        int i = base + tid;
        int v = (i < N_NODES) ? deg[i] : 0;
        buf[tid] = v;
        __syncthreads();
        for (int off = 1; off < 1024; off <<= 1) {
            int t = (tid >= off) ? buf[tid - off] : 0;
            __syncthreads();
            buf[tid] += t;
            __syncthreads();
        }
        int carry = carry_s;
        if (i < N_NODES) row_ptr[i + 1] = carry + buf[tid];
        __syncthreads();
        if (tid == 0) carry_s = carry + buf[1023];
        __syncthreads();
    }
}

__global__ void scatter_kernel(const int* __restrict__ src, const int* __restrict__ dst,
                               int* __restrict__ cursor, int* __restrict__ adj) {
    int i = blockIdx.x * 256 + threadIdx.x;
    if (i < N_EDGES) {
        int d = dst[i];
        int pos = atomicAdd(&cursor[d], 1);
        adj[pos] = src[i];
    }
}

// ---------------- aggregation: one wave per node ----------------

__global__ __launch_bounds__(256) void agg_kernel(const float* __restrict__ h,
                                                  const int* __restrict__ row_ptr,
                                                  const int* __restrict__ adj,
                                                  float* __restrict__ neigh) {
    const int wave = threadIdx.x >> 6;
    const int lane = threadIdx.x & 63;
    const int n = blockIdx.x * 4 + wave;
    if (n >= N_NODES) return;
    const int s = row_ptr[n];
    const int e = row_ptr[n + 1];
    float ax = 0.f, ay = 0.f;
    for (int i = s; i < e; i++) {
        int sr = adj[i];
        float2 v = *(const float2*)&h[(size_t)sr * DF + lane * 2];
        ax += v.x;
        ay += v.y;
    }
    int d = e - s;
    if (d < 1) d = 1;
    float inv = 1.0f / (float)d;
    float2 r;
    r.x = ax * inv;
    r.y = ay * inv;
    *(float2*)&neigh[(size_t)n * DF + lane * 2] = r;
}

// ---------------- fused GEMM: out = act([h | neigh] @ [Ws; Wn] + b) ----------------
// block: 256 threads, 32 output cols staged in LDS (256x32 fp32 = 32KB)
// thread tile: 8 nodes x 4 cols; block tile: 256 nodes x 32 cols

template <bool RELU>
__global__ __launch_bounds__(256) void gemm_kernel(const float* __restrict__ hin,
                                                   const float* __restrict__ neigh,
                                                   const float* __restrict__ wS,
                                                   const float* __restrict__ wN,
                                                   const float* __restrict__ bias,
                                                   float* __restrict__ out) {
    __shared__ float Wl[256 * 32];
    const int tid = threadIdx.x;
    const int c0 = blockIdx.x * 32;
    const int nbase = blockIdx.y * 256;

    for (int i = tid; i < 256 * 32; i += 256) {
        int k = i >> 5, cc = i & 31;
        Wl[i] = (k < 128) ? wS[k * 128 + c0 + cc] : wN[(k - 128) * 128 + c0 + cc];
    }
    __syncthreads();

    const int tc = tid & 7;
    const int tn = tid >> 3;
    const int cl = tc * 4;
    const int n0 = nbase + tn * 8;

    const float* xp[8];
#pragma unroll
    for (int i = 0; i < 8; i++) {
        int n = n0 + i;
        if (n > N_NODES - 1) n = N_NODES - 1;
        xp[i] = hin + (size_t)n * DF;
    }

    float4 acc[8];
#pragma unroll
    for (int i = 0; i < 8; i++) acc[i] = make_float4(0.f, 0.f, 0.f, 0.f);

    // self-weight half: k in [0,128)
    for (int k = 0; k < 128; k += 4) {
        float4 w0 = *(const float4*)&Wl[(k + 0) * 32 + cl];
        float4 w1 = *(const float4*)&Wl[(k + 1) * 32 + cl];
        float4 w2 = *(const float4*)&Wl[(k + 2) * 32 + cl];
        float4 w3 = *(const float4*)&Wl[(k + 3) * 32 + cl];
#pragma unroll
        for (int i = 0; i < 8; i++) {
            float4 x = *(const float4*)(xp[i] + k);
            acc[i].x = fmaf(x.x, w0.x, fmaf(x.y, w1.x, fmaf(x.z, w2.x, fmaf(x.w, w3.x, acc[i].x))));
            acc[i].y = fmaf(x.x, w0.y, fmaf(x.y, w1.y, fmaf(x.z, w2.y, fmaf(x.w, w3.y, acc[i].y))));
            acc[i].z = fmaf(x.x, w0.z, fmaf(x.y, w1.z, fmaf(x.z, w2.z, fmaf(x.w, w3.z, acc[i].z))));
            acc[i].w = fmaf(x.x, w0.w, fmaf(x.y, w1.w, fmaf(x.z, w2.w, fmaf(x.w, w3.w, acc[i].w))));
        }
    }

    // neighbor-weight half: k in [128,256)
#pragma unroll
    for (int i = 0; i < 8; i++) {
        int n = n0 + i;
        if (n > N_NODES - 1) n = N_NODES - 1;
        xp[i] = neigh + (size_t)n * DF;
    }
    for (int k = 0; k < 128; k += 4) {
        float4 w0 = *(const float4*)&Wl[(128 + k + 0) * 32 + cl];
        float4 w1 = *(const float4*)&Wl[(128 + k + 1) * 32 + cl];
        float4 w2 = *(const float4*)&Wl[(128 + k + 2) * 32 + cl];
        float4 w3 = *(const float4*)&Wl[(128 + k + 3) * 32 + cl];
#pragma unroll
        for (int i = 0; i < 8; i++) {
            float4 x = *(const float4*)(xp[i] + k);
            acc[i].x = fmaf(x.x, w0.x, fmaf(x.y, w1.x, fmaf(x.z, w2.x, fmaf(x.w, w3.x, acc[i].x))));
            acc[i].y = fmaf(x.x, w0.y, fmaf(x.y, w1.y, fmaf(x.z, w2.y, fmaf(x.w, w3.y, acc[i].y))));
            acc[i].z = fmaf(x.x, w0.z, fmaf(x.y, w1.z, fmaf(x.z, w2.z, fmaf(x.w, w3.z, acc[i].z))));
            acc[i].w = fmaf(x.x, w0.w, fmaf(x.y, w1.w, fmaf(x.z, w2.w, fmaf(x.w, w3.w, acc[i].w))));
        }
    }

    float4 bb = *(const float4*)&bias[c0 + cl];
#pragma unroll
    for (int i = 0; i < 8; i++) {
        int n = n0 + i;
        if (n < N_NODES) {
            float4 r;
            r.x = acc[i].x + bb.x;
            r.y = acc[i].y + bb.y;
            r.z = acc[i].z + bb.z;
            r.w = acc[i].w + bb.w;
            if (RELU) {
                r.x = fmaxf(r.x, 0.f);
                r.y = fmaxf(r.y, 0.f);
                r.z = fmaxf(r.z, 0.f);
                r.w = fmaxf(r.w, 0.f);
            }
            *(float4*)&out[(size_t)n * DF + c0 + cl] = r;
        }
    }
}

// ---------------- launch ----------------

extern "C" void kernel_launch(void* const* d_in, const int* in_sizes, int n_in,
                              void* d_out, int out_size, void* d_ws, size_t ws_size,
                              hipStream_t stream) {
    const float* feats = (const float*)d_in[0];
    const int* src = (const int*)d_in[1];
    const int* dst = (const int*)d_in[2];
    const float* wS[3] = {(const float*)d_in[3], (const float*)d_in[6], (const float*)d_in[9]};
    const float* wN[3] = {(const float*)d_in[4], (const float*)d_in[7], (const float*)d_in[10]};
    const float* bb[3] = {(const float*)d_in[5], (const float*)d_in[8], (const float*)d_in[11]};
    float* out = (float*)d_out;

    // workspace carve-up
    char* p = (char*)d_ws;
    auto alloc = [&](size_t bytes) {
        char* r = p;
        p += (bytes + 255) & ~(size_t)255;
        return r;
    };
    float* neigh = (float*)alloc((size_t)N_NODES * DF * sizeof(float));   // 25.6 MB
    float* hA = (float*)alloc((size_t)N_NODES * DF * sizeof(float));      // 25.6 MB
    int* deg = (int*)alloc((size_t)N_NODES * sizeof(int));
    int* row_ptr = (int*)alloc((size_t)(N_NODES + 1) * sizeof(int));
    int* cursor = (int*)alloc((size_t)N_NODES * sizeof(int));
    int* adj = (int*)alloc((size_t)N_EDGES * sizeof(int));                // 6.4 MB

    const int EB = (N_EDGES + 255) / 256;

    // CSR build (once per call, reused by all 3 layers)
    hipMemsetAsync(deg, 0, (size_t)N_NODES * sizeof(int), stream);
    deg_kernel<<<EB, 256, 0, stream>>>(dst, deg);
    scan_kernel<<<1, 1024, 0, stream>>>(deg, row_ptr);
    hipMemcpyAsync(cursor, row_ptr, (size_t)N_NODES * sizeof(int),
                   hipMemcpyDeviceToDevice, stream);
    scatter_kernel<<<EB, 256, 0, stream>>>(src, dst, cursor, adj);

    const int AGG_GRID = (N_NODES + 3) / 4;
    dim3 ggrid(4, (N_NODES + 255) / 256);

    // layer 0: feats -> d_out
    agg_kernel<<<AGG_GRID, 256, 0, stream>>>(feats, row_ptr, adj, neigh);
    gemm_kernel<true><<<ggrid, 256, 0, stream>>>(feats, neigh, wS[0], wN[0], bb[0], out);
    // layer 1: d_out -> hA
    agg_kernel<<<AGG_GRID, 256, 0, stream>>>(out, row_ptr, adj, neigh);
    gemm_kernel<true><<<ggrid, 256, 0, stream>>>(out, neigh, wS[1], wN[1], bb[1], hA);
    // layer 2: hA -> d_out
    agg_kernel<<<AGG_GRID, 256, 0, stream>>>(hA, row_ptr, adj, neigh);
    gemm_kernel<false><<<ggrid, 256, 0, stream>>>(hA, neigh, wS[2], wN[2], bb[2], out);
}

// Round 3
// 768.352 us; speedup vs baseline: 1.5598x; 1.5598x over previous
//
#include <hip/hip_runtime.h>
#include <hip/hip_bf16.h>

#define N_NODES 50000
#define N_EDGES 1600000
#define DF 128

// ---------------- CSR build ----------------

__global__ void deg_kernel(const int* __restrict__ dst, int* __restrict__ deg) {
    int i = blockIdx.x * 256 + threadIdx.x;
    if (i < N_EDGES) atomicAdd(&deg[dst[i]], 1);
}

// block-scan + atomic bump allocator: rstart[n] = contiguous region of size deg[n].
// Region order across blocks is arbitrary (atomic) but CSR stays valid.
__global__ __launch_bounds__(256) void alloc_kernel(const int* __restrict__ degv,
                                                    int* __restrict__ rstart,
                                                    int* __restrict__ counter) {
    __shared__ int buf[256];
    __shared__ int base_s;
    const int tid = threadIdx.x;
    const int i = blockIdx.x * 256 + tid;
    int v = (i < N_NODES) ? degv[i] : 0;
    buf[tid] = v;
    __syncthreads();
#pragma unroll
    for (int off = 1; off < 256; off <<= 1) {
        int t = (tid >= off) ? buf[tid - off] : 0;
        __syncthreads();
        buf[tid] += t;
        __syncthreads();
    }
    if (tid == 255) base_s = atomicAdd(counter, buf[255]);
    __syncthreads();
    if (i < N_NODES) rstart[i] = base_s + buf[tid] - v;  // exclusive within block + block base
}

__global__ void scatter_kernel(const int* __restrict__ src, const int* __restrict__ dst,
                               int* __restrict__ cursor, int* __restrict__ adj) {
    int i = blockIdx.x * 256 + threadIdx.x;
    if (i < N_EDGES) {
        int d = dst[i];
        int pos = atomicAdd(&cursor[d], 1);
        adj[pos] = src[i];
    }
}

// ---------------- aggregation: one wave per node, 4 rows in flight ----------------

__global__ __launch_bounds__(256) void agg_kernel(const float* __restrict__ h,
                                                  const int* __restrict__ rstart,
                                                  const int* __restrict__ degv,
                                                  const int* __restrict__ adj,
                                                  float* __restrict__ neigh) {
    const int wave = threadIdx.x >> 6;
    const int lane = threadIdx.x & 63;
    const int n = blockIdx.x * 4 + wave;
    if (n >= N_NODES) return;
    const int s = rstart[n];
    const int d = degv[n];
    const size_t off = (size_t)(lane * 2);
    float ax0 = 0.f, ay0 = 0.f, ax1 = 0.f, ay1 = 0.f;
    float ax2 = 0.f, ay2 = 0.f, ax3 = 0.f, ay3 = 0.f;
    int i = 0;
    for (; i + 4 <= d; i += 4) {
        int s0 = adj[s + i + 0];
        int s1 = adj[s + i + 1];
        int s2 = adj[s + i + 2];
        int s3 = adj[s + i + 3];
        float2 v0 = *(const float2*)&h[(size_t)s0 * DF + off];
        float2 v1 = *(const float2*)&h[(size_t)s1 * DF + off];
        float2 v2 = *(const float2*)&h[(size_t)s2 * DF + off];
        float2 v3 = *(const float2*)&h[(size_t)s3 * DF + off];
        ax0 += v0.x; ay0 += v0.y;
        ax1 += v1.x; ay1 += v1.y;
        ax2 += v2.x; ay2 += v2.y;
        ax3 += v3.x; ay3 += v3.y;
    }
    for (; i < d; i++) {
        int s0 = adj[s + i];
        float2 v = *(const float2*)&h[(size_t)s0 * DF + off];
        ax0 += v.x; ay0 += v.y;
    }
    float inv = 1.0f / (float)(d < 1 ? 1 : d);
    float2 r;
    r.x = (ax0 + ax1 + ax2 + ax3) * inv;
    r.y = (ay0 + ay1 + ay2 + ay3) * inv;
    *(float2*)&neigh[(size_t)n * DF + off] = r;
}

// ---------------- fused GEMM: out = act([h | neigh] @ [Ws; Wn] + b) ----------------
// Block tile 128 nodes x 128 cols (all cols), 256 threads, 8x8 register tile.
// X tile staged in LDS with chunk-rotation swizzle (conflict-free b128 reads);
// W panel (32 k x 128 c) staged linearly. FMA-bound by design.

template <bool RELU>
__global__ __launch_bounds__(256, 1) void gemm_kernel(const float* __restrict__ hin,
                                                      const float* __restrict__ neigh,
                                                      const float* __restrict__ wS,
                                                      const float* __restrict__ wN,
                                                      const float* __restrict__ bias,
                                                      float* __restrict__ out) {
    __shared__ float Xs[128 * 32];   // [node][32k], 16B chunks rotated by (node>>3)&7
    __shared__ float Ws[32 * 128];   // [k][c], linear

    const int tid = threadIdx.x;
    const int nbase = blockIdx.x * 128;
    const int tn = tid >> 4;   // 0..15 node group
    const int tc = tid & 15;   // 0..15 col group (cols tc*4..+3 and 64+tc*4..+3)
    const int rot = tn & 7;

    float acc[8][8];
#pragma unroll
    for (int i = 0; i < 8; i++)
#pragma unroll
        for (int j = 0; j < 8; j++) acc[i][j] = 0.f;

    const float* Xsrc[2] = {hin, neigh};
    const float* Wsrc[2] = {wS, wN};

    for (int half = 0; half < 2; ++half) {
        const float* X = Xsrc[half];
        const float* W = Wsrc[half];
        for (int k0 = 0; k0 < 128; k0 += 32) {
            __syncthreads();  // protect previous iteration's LDS reads
            // --- stage X: linear LDS fill; source chunk chosen so that chunk c of
            // node m lands at position (c + rot(m)) & 7  (rot(m) = (m>>3)&7)
            {
                float4* dstv = (float4*)Xs;
#pragma unroll
                for (int j = 0; j < 4; j++) {
                    int sidx = tid + j * 256;          // float4 slot 0..1023
                    int node = sidx >> 3;              // 0..127
                    int cp = sidx & 7;                 // chunk position
                    int c = (cp - ((node >> 3) & 7)) & 7;
                    int n = nbase + node;
                    if (n > N_NODES - 1) n = N_NODES - 1;
                    dstv[sidx] = *(const float4*)(X + (size_t)n * DF + k0 + c * 4);
                }
            }
            // --- stage W: 32x128 contiguous
            {
                const float4* srcv = (const float4*)(W + (size_t)k0 * 128);
                float4* dstv = (float4*)Ws;
#pragma unroll
                for (int j = 0; j < 4; j++) dstv[tid + j * 256] = srcv[tid + j * 256];
            }
            __syncthreads();
            // --- compute
#pragma unroll
            for (int q = 0; q < 8; q++) {  // kk chunk of 4
                float4 x[8];
#pragma unroll
                for (int i = 0; i < 8; i++) {
                    x[i] = *(const float4*)&Xs[(tn * 8 + i) * 32 + (((q + rot) & 7) * 4)];
                }
                float4 wlo[4], whi[4];
#pragma unroll
                for (int p = 0; p < 4; p++) {
                    wlo[p] = *(const float4*)&Ws[(q * 4 + p) * 128 + tc * 4];
                    whi[p] = *(const float4*)&Ws[(q * 4 + p) * 128 + 64 + tc * 4];
                }
#pragma unroll
                for (int i = 0; i < 8; i++) {
                    acc[i][0] = fmaf(x[i].x, wlo[0].x, fmaf(x[i].y, wlo[1].x, fmaf(x[i].z, wlo[2].x, fmaf(x[i].w, wlo[3].x, acc[i][0]))));
                    acc[i][1] = fmaf(x[i].x, wlo[0].y, fmaf(x[i].y, wlo[1].y, fmaf(x[i].z, wlo[2].y, fmaf(x[i].w, wlo[3].y, acc[i][1]))));
                    acc[i][2] = fmaf(x[i].x, wlo[0].z, fmaf(x[i].y, wlo[1].z, fmaf(x[i].z, wlo[2].z, fmaf(x[i].w, wlo[3].z, acc[i][2]))));
                    acc[i][3] = fmaf(x[i].x, wlo[0].w, fmaf(x[i].y, wlo[1].w, fmaf(x[i].z, wlo[2].w, fmaf(x[i].w, wlo[3].w, acc[i][3]))));
                    acc[i][4] = fmaf(x[i].x, whi[0].x, fmaf(x[i].y, whi[1].x, fmaf(x[i].z, whi[2].x, fmaf(x[i].w, whi[3].x, acc[i][4]))));
                    acc[i][5] = fmaf(x[i].x, whi[0].y, fmaf(x[i].y, whi[1].y, fmaf(x[i].z, whi[2].y, fmaf(x[i].w, whi[3].y, acc[i][5]))));
                    acc[i][6] = fmaf(x[i].x, whi[0].z, fmaf(x[i].y, whi[1].z, fmaf(x[i].z, whi[2].z, fmaf(x[i].w, whi[3].z, acc[i][6]))));
                    acc[i][7] = fmaf(x[i].x, whi[0].w, fmaf(x[i].y, whi[1].w, fmaf(x[i].z, whi[2].w, fmaf(x[i].w, whi[3].w, acc[i][7]))));
                }
            }
        }
    }

    // --- epilogue
    float4 b_lo = *(const float4*)&bias[tc * 4];
    float4 b_hi = *(const float4*)&bias[64 + tc * 4];
#pragma unroll
    for (int i = 0; i < 8; i++) {
        int n = nbase + tn * 8 + i;
        if (n < N_NODES) {
            float4 r0, r1;
            r0.x = acc[i][0] + b_lo.x; r0.y = acc[i][1] + b_lo.y;
            r0.z = acc[i][2] + b_lo.z; r0.w = acc[i][3] + b_lo.w;
            r1.x = acc[i][4] + b_hi.x; r1.y = acc[i][5] + b_hi.y;
            r1.z = acc[i][6] + b_hi.z; r1.w = acc[i][7] + b_hi.w;
            if (RELU) {
                r0.x = fmaxf(r0.x, 0.f); r0.y = fmaxf(r0.y, 0.f);
                r0.z = fmaxf(r0.z, 0.f); r0.w = fmaxf(r0.w, 0.f);
                r1.x = fmaxf(r1.x, 0.f); r1.y = fmaxf(r1.y, 0.f);
                r1.z = fmaxf(r1.z, 0.f); r1.w = fmaxf(r1.w, 0.f);
            }
            *(float4*)&out[(size_t)n * DF + tc * 4] = r0;
            *(float4*)&out[(size_t)n * DF + 64 + tc * 4] = r1;
        }
    }
}

// ---------------- launch ----------------

extern "C" void kernel_launch(void* const* d_in, const int* in_sizes, int n_in,
                              void* d_out, int out_size, void* d_ws, size_t ws_size,
                              hipStream_t stream) {
    const float* feats = (const float*)d_in[0];
    const int* src = (const int*)d_in[1];
    const int* dst = (const int*)d_in[2];
    const float* wS[3] = {(const float*)d_in[3], (const float*)d_in[6], (const float*)d_in[9]};
    const float* wN[3] = {(const float*)d_in[4], (const float*)d_in[7], (const float*)d_in[10]};
    const float* bb[3] = {(const float*)d_in[5], (const float*)d_in[8], (const float*)d_in[11]};
    float* out = (float*)d_out;

    char* p = (char*)d_ws;
    auto alloc = [&](size_t bytes) {
        char* r = p;
        p += (bytes + 255) & ~(size_t)255;
        return r;
    };
    float* neigh = (float*)alloc((size_t)N_NODES * DF * sizeof(float));   // 25.6 MB
    float* hA = (float*)alloc((size_t)N_NODES * DF * sizeof(float));      // 25.6 MB
    int* deg = (int*)alloc((size_t)N_NODES * sizeof(int));
    int* rstart = (int*)alloc((size_t)N_NODES * sizeof(int));
    int* cursor = (int*)alloc((size_t)N_NODES * sizeof(int));
    int* counter = (int*)alloc(sizeof(int));
    int* adj = (int*)alloc((size_t)N_EDGES * sizeof(int));                // 6.4 MB

    const int EB = (N_EDGES + 255) / 256;
    const int NB = (N_NODES + 255) / 256;

    // CSR build (reused by all 3 layers)
    hipMemsetAsync(deg, 0, (size_t)N_NODES * sizeof(int), stream);
    hipMemsetAsync(counter, 0, sizeof(int), stream);
    deg_kernel<<<EB, 256, 0, stream>>>(dst, deg);
    alloc_kernel<<<NB, 256, 0, stream>>>(deg, rstart, counter);
    hipMemcpyAsync(cursor, rstart, (size_t)N_NODES * sizeof(int),
                   hipMemcpyDeviceToDevice, stream);
    scatter_kernel<<<EB, 256, 0, stream>>>(src, dst, cursor, adj);

    const int AGG_GRID = (N_NODES + 3) / 4;
    const int GB = (N_NODES + 127) / 128;

    // layer 0: feats -> d_out
    agg_kernel<<<AGG_GRID, 256, 0, stream>>>(feats, rstart, deg, adj, neigh);
    gemm_kernel<true><<<GB, 256, 0, stream>>>(feats, neigh, wS[0], wN[0], bb[0], out);
    // layer 1: d_out -> hA
    agg_kernel<<<AGG_GRID, 256, 0, stream>>>(out, rstart, deg, adj, neigh);
    gemm_kernel<true><<<GB, 256, 0, stream>>>(out, neigh, wS[1], wN[1], bb[1], hA);
    // layer 2: hA -> d_out
    agg_kernel<<<AGG_GRID, 256, 0, stream>>>(hA, rstart, deg, adj, neigh);
    gemm_kernel<false><<<GB, 256, 0, stream>>>(hA, neigh, wS[2], wN[2], bb[2], out);
}